// Round 7
// baseline (339.051 us; speedup 1.0000x reference)
//
#include <hip/hip_runtime.h>
#include <math.h>

// ---------------------------------------------------------------------------
// GCN 3-layer forward, bf16 + MFMA, 5 dispatches:
//   memset(cnt); SOUP{gemm1->T1(sliced) + binned CSR fill(u16,nt) + packW2/W3};
//   AGGEMM1{agg1->LDS->gemm2->T2(sliced)}; AGGEMM2{agg2->LDS->gemm3->T3};
//   AGG3+LSM.
// KEY (R7): gather tables stored as 4 column-slices [n][32] bf16 (3.2MB each,
// < 4MB per-XCD L2). Aggregation loops slices; all blocks sweep the same
// slice ~concurrently -> gathers are L2 hits instead of L3 (R6 was
// L2-miss-latency-bound: 12.8MB table vs 4MB L2).
// Aggregated H lives ONLY in LDS (no H round-trip).
//   out[d] = dn_d * ( dn_d*T[d] + sum_s dn_s*T[s] ) + b, dn = rsqrt(cnt+1)
// ---------------------------------------------------------------------------

typedef short s8v __attribute__((ext_vector_type(8)));
typedef float f4v __attribute__((ext_vector_type(4)));
typedef unsigned short u16;

#define CSR_CAP 64

__device__ inline unsigned short f2b(float f) {  // f32 -> bf16 RNE
  unsigned int u = __float_as_uint(f);
  return (unsigned short)((u + 0x7fffu + ((u >> 16) & 1u)) >> 16);
}
__device__ inline float b2f(unsigned short b) {
  return __uint_as_float(((unsigned int)b) << 16);
}
__device__ inline f4v mfma16(s8v a, s8v b, f4v c) {
  return __builtin_amdgcn_mfma_f32_16x16x32_bf16(a, b, c, 0, 0, 0);
}

// W [128][FOUT_real] f32 -> bf16 MFMA B-fragment order (zero-padded):
//   Wp[((ks*NCT+ct)*64+lane)*8+j] = W[ks*32+(lane>>4)*8+j][ct*16+(lane&15)]
__device__ inline void pack_w_elem(const float* __restrict__ W,
                                   short* __restrict__ Wp, int FOUT_real,
                                   int NCT, int idx) {
  const int j = idx & 7;
  const int lane = (idx >> 3) & 63;
  const int fct = idx >> 9;
  const int ks = fct / NCT, ct = fct - ks * NCT;
  const int k = ks * 32 + (lane >> 4) * 8 + j;
  const int c = ct * 16 + (lane & 15);
  const float v = (c < FOUT_real) ? W[k * FOUT_real + c] : 0.f;
  Wp[idx] = (short)f2b(v);
}

// ---------------- SOUP: gemm1 | binned fill | packW2 | packW3 ----------------
__global__ __launch_bounds__(256) void k_soup(
    const float* __restrict__ x, const float* __restrict__ W1,
    short* __restrict__ Tb1, size_t SS, int nRowTiles, int gemmNB,
    const int* __restrict__ src, const int* __restrict__ dst,
    int* __restrict__ cnt, u16* __restrict__ col, int e, float inv8n,
    int fillNB, const float* __restrict__ W2, short* __restrict__ Wp2,
    const float* __restrict__ W3, short* __restrict__ Wp3) {
  __shared__ short Ws[4 * 8 * 64 * 8];  // 32 KB (gemm role only)
  const int bid = blockIdx.x;
  const int tid = threadIdx.x;

  if (bid < gemmNB) {
    // ---- layer-1 GEMM: pack W1 (f32) into LDS fragment order, then MFMA ----
    const float4* w4 = (const float4*)W1;
    for (int it = 0; it < 16; ++it) {
      const int lin4 = it * 256 + tid;  // 0..4095 over 128x128 f32
      const int k = lin4 >> 5;
      const float4 v = w4[lin4];
      const int cb = (lin4 & 31) * 4;
      const int ks = k >> 5, kr = k & 31;
      const int laneBase = (kr >> 3) << 4;
      const int j = kr & 7;
      const float fv[4] = {v.x, v.y, v.z, v.w};
#pragma unroll
      for (int q = 0; q < 4; ++q) {
        const int c = cb + q;
        Ws[((ks * 8 + (c >> 4)) * 64 + (laneBase | (c & 15))) * 8 + j] =
            (short)f2b(fv[q]);
      }
    }
    __syncthreads();
    const int wid = tid >> 6, lane = tid & 63;
    const int rowTile = bid * 4 + wid;
    if (rowTile >= nRowTiles) return;
    const int row0 = rowTile * 16;
    const int arow = row0 + (lane & 15);
    const int kcol = (lane >> 4) * 8;
    f4v acc[8];
#pragma unroll
    for (int ct = 0; ct < 8; ++ct) acc[ct] = (f4v)(0.f);
    const float* ap = x + (size_t)arow * 128 + kcol;
#pragma unroll
    for (int ks = 0; ks < 4; ++ks) {
      const float4 a0 = *(const float4*)(ap + ks * 32);
      const float4 a1 = *(const float4*)(ap + ks * 32 + 4);
      s8v af;
      af[0] = (short)f2b(a0.x); af[1] = (short)f2b(a0.y);
      af[2] = (short)f2b(a0.z); af[3] = (short)f2b(a0.w);
      af[4] = (short)f2b(a1.x); af[5] = (short)f2b(a1.y);
      af[6] = (short)f2b(a1.z); af[7] = (short)f2b(a1.w);
#pragma unroll
      for (int ct = 0; ct < 8; ++ct) {
        const s8v bf = *(const s8v*)(Ws + ((ks * 8 + ct) * 64 + lane) * 8);
        acc[ct] = mfma16(af, bf, acc[ct]);
      }
    }
    // C/D: col = lane&15 (+16*ct), row = (lane>>4)*4 + r ; sliced T1 write
    const int crow0 = row0 + (lane >> 4) * 4;
    const int ccol = lane & 15;
#pragma unroll
    for (int r = 0; r < 4; ++r) {
      short* orow = Tb1 + (size_t)(crow0 + r) * 32 + ccol;
#pragma unroll
      for (int ct = 0; ct < 8; ++ct)
        orow[(size_t)(ct >> 1) * SS + (ct & 1) * 16] = (short)f2b(acc[ct][r]);
    }
  } else if (bid < gemmNB + fillNB) {
    // ---- binned CSR fill: this block handles dst bin (fb&7) only ----
    const int fb = bid - gemmNB;
    const int bin = fb & 7;
    const int scanB = fb >> 3;
    const int stride = (fillNB >> 3) * 256;
    for (int i = scanB * 256 + tid; i < e; i += stride) {
      const int d = dst[i];
      int b = (int)((float)d * inv8n);
      b = b > 7 ? 7 : b;
      if (b == bin) {
        const int idx = atomicAdd(&cnt[d], 1);
        __builtin_nontemporal_store((u16)src[i], &col[(size_t)d * CSR_CAP + idx]);
      }
    }
  } else {
    int pb = bid - gemmNB - fillNB;
    if (pb < 64) {
      pack_w_elem(W2, Wp2, 128, 8, pb * 256 + tid);
    } else {
      const int idx = (pb - 64) * 256 + tid;
      if (idx < 128 * 48) pack_w_elem(W3, Wp3, 40, 3, idx);
    }
  }
}

// ------- AGGEMM (sliced): agg 128 nodes (slice-major, L2-hit) -> LDS -> MFMA
// Phase A: for sl=0..3: H[:, sl*32 : sl*32+32] = relu(dn*(agg)+bias) -> LDS.
// Phase B: Tout = H @ Wp (unscaled); Tout sliced (FOUT=128) or flat (48).
template <int FOUT>
__global__ __launch_bounds__(512) void k_aggemm_s(
    const short* __restrict__ Tsl, const int* __restrict__ cnt,
    const u16* __restrict__ col, const float* __restrict__ bias,
    const short* __restrict__ Wp, short* __restrict__ Tout, size_t SS, int n) {
  __shared__ short Ht[128 * 128];  // 32 KB, XOR-swizzled rows
  const int tid = threadIdx.x;
  const int base = blockIdx.x * 128;

  // ---- phase A: 4 lanes/node (16B each), one slice at a time ----
  const int nl = tid >> 2;       // node-local 0..127
  const int node = base + nl;
  const int c0 = (tid & 3) * 8;  // col-in-slice
  int cn = 0;
  float dn = 0.f;
  const u16* cp = col + (size_t)node * CSR_CAP;
  if (node < n) {
    cn = cnt[node];
    dn = rsqrtf((float)(cn + 1));
  }
#pragma unroll
  for (int sl = 0; sl < 4; ++sl) {
    const short* Ts = Tsl + (size_t)sl * SS;
    float acc[8];
#pragma unroll
    for (int j = 0; j < 8; ++j) acc[j] = 0.f;
    if (node < n) {
      const s8v v = *(const s8v*)(Ts + (size_t)node * 32 + c0);  // self
#pragma unroll
      for (int j = 0; j < 8; ++j) acc[j] = dn * b2f((unsigned short)v[j]);
      for (int k = 0; k < cn; ++k) {
        const int s = cp[k];
        const float ds = rsqrtf((float)(cnt[s] + 1));
        const s8v v2 = *(const s8v*)(Ts + (size_t)s * 32 + c0);
#pragma unroll
        for (int j = 0; j < 8; ++j) acc[j] += ds * b2f((unsigned short)v2[j]);
      }
    }
    const int cc = sl * 32 + c0;
    s8v o;
#pragma unroll
    for (int j = 0; j < 8; ++j) {
      const float r = (node < n) ? fmaxf(acc[j] * dn + bias[cc + j], 0.f) : 0.f;
      o[j] = (short)f2b(r);
    }
    *(s8v*)((char*)Ht + nl * 256 + ((cc * 2) ^ ((nl & 7) << 4))) = o;
  }
  __syncthreads();

  // ---- phase B: 8 waves x 16-row tiles, full FOUT per wave ----
  constexpr int NCT = FOUT / 16;
  const int wid = tid >> 6, lane = tid & 63;
  const int lrow = wid * 16 + (lane & 15);
  const int kbase = (lane >> 4) * 8;
  f4v acc[NCT];
#pragma unroll
  for (int j = 0; j < NCT; ++j) acc[j] = (f4v)(0.f);
#pragma unroll
  for (int ks = 0; ks < 4; ++ks) {
    const int kcol = ks * 32 + kbase;
    const s8v af = *(const s8v*)((const char*)Ht + lrow * 256 +
                                 ((kcol * 2) ^ ((lrow & 7) << 4)));
#pragma unroll
    for (int j = 0; j < NCT; ++j) {
      const s8v bf = *(const s8v*)(Wp + ((ks * NCT + j) * 64 + lane) * 8);
      acc[j] = mfma16(af, bf, acc[j]);
    }
  }
  const int crow0 = base + wid * 16 + (lane >> 4) * 4;
  const int ccol = lane & 15;
#pragma unroll
  for (int r = 0; r < 4; ++r) {
#pragma unroll
    for (int j = 0; j < NCT; ++j) {
      const short v = (short)f2b(acc[j][r]);
      if (FOUT == 128)
        Tout[(size_t)(j >> 1) * SS + (size_t)(crow0 + r) * 32 + (j & 1) * 16 +
             ccol] = v;
      else
        Tout[(size_t)(crow0 + r) * FOUT + j * 16 + ccol] = v;
    }
  }
}

// ---------------- agg3 + log_softmax fused (T3 flat 48-wide, 40 valid) ------
__global__ __launch_bounds__(256) void k_agg3_lsm(const short* __restrict__ Tb,
                                                  const int* __restrict__ cnt,
                                                  const u16* __restrict__ col,
                                                  const float* __restrict__ bias,
                                                  float* __restrict__ out, int n) {
  const int gtid = blockIdx.x * 256 + threadIdx.x;
  const int node = gtid >> 3;
  const int c8 = gtid & 7;
  if (node >= n) return;
  const int c0 = c8 * 8;
  const bool valid = c8 < 5;
  const int cn = cnt[node];
  const float dn = rsqrtf((float)(cn + 1));
  float acc[8];
#pragma unroll
  for (int j = 0; j < 8; ++j) acc[j] = 0.f;
  if (valid) {
    const s8v v = *(const s8v*)(Tb + (size_t)node * 48 + c0);
#pragma unroll
    for (int j = 0; j < 8; ++j) acc[j] = dn * b2f((unsigned short)v[j]);
  }
  const u16* cp = col + (size_t)node * CSR_CAP;
  for (int k = 0; k < cn; ++k) {
    const int s = cp[k];
    if (valid) {
      const float ds = rsqrtf((float)(cnt[s] + 1));
      const s8v v = *(const s8v*)(Tb + (size_t)s * 48 + c0);
#pragma unroll
      for (int j = 0; j < 8; ++j) acc[j] += ds * b2f((unsigned short)v[j]);
    }
  }
  float r[8];
  float m = -INFINITY;
#pragma unroll
  for (int j = 0; j < 8; ++j) {
    r[j] = valid ? (acc[j] * dn + bias[c0 + j]) : -INFINITY;
    m = fmaxf(m, r[j]);
  }
#pragma unroll
  for (int w = 1; w < 8; w <<= 1) m = fmaxf(m, __shfl_xor(m, w, 64));
  float s = 0.f;
#pragma unroll
  for (int j = 0; j < 8; ++j) s += expf(r[j] - m);
#pragma unroll
  for (int w = 1; w < 8; w <<= 1) s += __shfl_xor(s, w, 64);
  const float ls = logf(s);
  if (valid) {
    float* op = out + (size_t)node * 40 + c0;
    *(float4*)op = make_float4(r[0] - m - ls, r[1] - m - ls, r[2] - m - ls,
                               r[3] - m - ls);
    *(float4*)(op + 4) = make_float4(r[4] - m - ls, r[5] - m - ls,
                                     r[6] - m - ls, r[7] - m - ls);
  }
}

extern "C" void kernel_launch(void* const* d_in, const int* in_sizes, int n_in,
                              void* d_out, int out_size, void* d_ws,
                              size_t ws_size, hipStream_t stream) {
  const float* x  = (const float*)d_in[0];
  const int*   ei = (const int*)d_in[1];
  const float* W1 = (const float*)d_in[2];
  const float* b1 = (const float*)d_in[3];
  const float* W2 = (const float*)d_in[4];
  const float* b2 = (const float*)d_in[5];
  const float* W3 = (const float*)d_in[6];
  const float* b3 = (const float*)d_in[7];
  float* out = (float*)d_out;

  const int n = in_sizes[0] / 128;  // 50000
  const int e = in_sizes[1] / 2;    // 800000
  const int* src = ei;
  const int* dst = ei + e;

  char* ws = (char*)d_ws;
  size_t off = 0;
  auto carve = [&](size_t bytes) -> void* {
    void* p = ws + off;
    off = (off + bytes + 255) & ~(size_t)255;
    return p;
  };
  const int nb128 = (n + 127) / 128;           // aggemm blocks (391)
  const size_t rows_pad = (size_t)nb128 * 128; // 50048
  const size_t SS = rows_pad * 32;             // elements per slice

  int*   cnt = (int*)carve((size_t)n * 4);
  u16*   col = (u16*)carve((size_t)n * CSR_CAP * 2);  // 6.4 MB padded CSR
  short* A   = (short*)carve(4 * SS * 2);             // T2 sliced
  short* B   = (short*)carve(4 * SS * 2);             // T1 sliced, then T3 flat [rows][48]
  short* Wp2 = (short*)carve(128 * 128 * 2);
  short* Wp3 = (short*)carve(128 * 48 * 2);

  const int nRowTiles = (n + 15) / 16;       // 3125
  const int gemmNB = (nRowTiles + 3) / 4;    // 782
  const int fillNB = 2048;                   // 256 scan-blocks x 8 bins
  const int soupNB = gemmNB + fillNB + 64 + 24;

  hipMemsetAsync(cnt, 0, (size_t)n * 4, stream);
  k_soup<<<soupNB, 256, 0, stream>>>(x, W1, B, SS, nRowTiles, gemmNB, src, dst,
                                     cnt, col, e, 8.0f / (float)n, fillNB,
                                     W2, Wp2, W3, Wp3);
  // Layer 1 agg + layer 2 gemm: B(T1 sliced) -> A(T2 sliced)
  k_aggemm_s<128><<<nb128, 512, 0, stream>>>(B, cnt, col, b1, Wp2, A, SS, n);
  // Layer 2 agg + layer 3 gemm: A(T2 sliced) -> B(T3 flat 48)
  k_aggemm_s<48><<<nb128, 512, 0, stream>>>(A, cnt, col, b2, Wp3, B, SS, n);
  // Layer 3 agg + log_softmax: B(T3) -> out
  k_agg3_lsm<<<((size_t)n * 8 + 255) / 256, 256, 0, stream>>>(B, cnt, col, b3,
                                                              out, n);
}

// Round 8
// 221.862 us; speedup vs baseline: 1.5282x; 1.5282x over previous
//
#include <hip/hip_runtime.h>
#include <math.h>

// ---------------------------------------------------------------------------
// GCN 3-layer forward, bf16 + MFMA, 6 dispatches:
//   memset(cnt); SOUP{gemm1->T1 + binned CSR fill(u16) + packW2/W3};
//   DINVF; AGGEMM1{agg1+gemm2->T2hat}; AGGEMM2{agg2+gemm3->T3hat}; AGG3+LSM.
// Algebra: T̂[row] = dn_row*(H@W)[row] applied in GEMM epilogues, so edge
// loops are PURE gather+add (layer1 gathers precomputed dnf[s] instead):
//   out[d] = dn_d*( T̂[d] + sum_s T̂[s] ) + b
// Edge loops 4x unrolled for memory-level parallelism (L3-latency-bound).
// R7 lesson: keep 256B/gather, lean loop; no slicing.
// ---------------------------------------------------------------------------

typedef short s8v __attribute__((ext_vector_type(8)));
typedef float f4v __attribute__((ext_vector_type(4)));
typedef unsigned short u16;

#define CSR_CAP 64

__device__ inline unsigned short f2b(float f) {  // f32 -> bf16 RNE
  unsigned int u = __float_as_uint(f);
  return (unsigned short)((u + 0x7fffu + ((u >> 16) & 1u)) >> 16);
}
__device__ inline float b2f(unsigned short b) {
  return __uint_as_float(((unsigned int)b) << 16);
}
__device__ inline f4v mfma16(s8v a, s8v b, f4v c) {
  return __builtin_amdgcn_mfma_f32_16x16x32_bf16(a, b, c, 0, 0, 0);
}

// W [128][FOUT_real] f32 -> bf16 MFMA B-fragment order (zero-padded):
__device__ inline void pack_w_elem(const float* __restrict__ W,
                                   short* __restrict__ Wp, int FOUT_real,
                                   int NCT, int idx) {
  const int j = idx & 7;
  const int lane = (idx >> 3) & 63;
  const int fct = idx >> 9;
  const int ks = fct / NCT, ct = fct - ks * NCT;
  const int k = ks * 32 + (lane >> 4) * 8 + j;
  const int c = ct * 16 + (lane & 15);
  const float v = (c < FOUT_real) ? W[k * FOUT_real + c] : 0.f;
  Wp[idx] = (short)f2b(v);
}

// ---------------- SOUP: gemm1 | binned fill | packW2 | packW3 ----------------
__global__ __launch_bounds__(256) void k_soup(
    const float* __restrict__ x, const float* __restrict__ W1,
    short* __restrict__ Tb1, int nRowTiles, int gemmNB,
    const int* __restrict__ src, const int* __restrict__ dst,
    int* __restrict__ cnt, u16* __restrict__ col, int e, float inv8n,
    int fillNB, const float* __restrict__ W2, short* __restrict__ Wp2,
    const float* __restrict__ W3, short* __restrict__ Wp3) {
  __shared__ short Ws[4 * 8 * 64 * 8];  // 32 KB (gemm role only)
  const int bid = blockIdx.x;
  const int tid = threadIdx.x;

  if (bid < gemmNB) {
    // ---- layer-1 GEMM: pack W1 (f32) into LDS fragment order, then MFMA ----
    const float4* w4 = (const float4*)W1;
    for (int it = 0; it < 16; ++it) {
      const int lin4 = it * 256 + tid;  // 0..4095 over 128x128 f32
      const int k = lin4 >> 5;
      const float4 v = w4[lin4];
      const int cb = (lin4 & 31) * 4;
      const int ks = k >> 5, kr = k & 31;
      const int laneBase = (kr >> 3) << 4;
      const int j = kr & 7;
      const float fv[4] = {v.x, v.y, v.z, v.w};
#pragma unroll
      for (int q = 0; q < 4; ++q) {
        const int c = cb + q;
        Ws[((ks * 8 + (c >> 4)) * 64 + (laneBase | (c & 15))) * 8 + j] =
            (short)f2b(fv[q]);
      }
    }
    __syncthreads();
    const int wid = tid >> 6, lane = tid & 63;
    const int rowTile = bid * 4 + wid;
    if (rowTile >= nRowTiles) return;
    const int row0 = rowTile * 16;
    const int arow = row0 + (lane & 15);
    const int kcol = (lane >> 4) * 8;
    f4v acc[8];
#pragma unroll
    for (int ct = 0; ct < 8; ++ct) acc[ct] = (f4v)(0.f);
    const float* ap = x + (size_t)arow * 128 + kcol;
#pragma unroll
    for (int ks = 0; ks < 4; ++ks) {
      const float4 a0 = *(const float4*)(ap + ks * 32);
      const float4 a1 = *(const float4*)(ap + ks * 32 + 4);
      s8v af;
      af[0] = (short)f2b(a0.x); af[1] = (short)f2b(a0.y);
      af[2] = (short)f2b(a0.z); af[3] = (short)f2b(a0.w);
      af[4] = (short)f2b(a1.x); af[5] = (short)f2b(a1.y);
      af[6] = (short)f2b(a1.z); af[7] = (short)f2b(a1.w);
#pragma unroll
      for (int ct = 0; ct < 8; ++ct) {
        const s8v bf = *(const s8v*)(Ws + ((ks * 8 + ct) * 64 + lane) * 8);
        acc[ct] = mfma16(af, bf, acc[ct]);
      }
    }
    // C/D: col = lane&15 (+16*ct), row = (lane>>4)*4 + r  (T1 UNSCALED)
    const int crow0 = row0 + (lane >> 4) * 4;
    const int ccol = lane & 15;
#pragma unroll
    for (int r = 0; r < 4; ++r) {
      short* orow = Tb1 + (size_t)(crow0 + r) * 128 + ccol;
#pragma unroll
      for (int ct = 0; ct < 8; ++ct) orow[ct * 16] = (short)f2b(acc[ct][r]);
    }
  } else if (bid < gemmNB + fillNB) {
    // ---- binned CSR fill: this block handles dst bin (fb&7) only ----
    const int fb = bid - gemmNB;
    const int bin = fb & 7;
    const int scanB = fb >> 3;
    const int stride = (fillNB >> 3) * 256;
    for (int i = scanB * 256 + tid; i < e; i += stride) {
      const int d = dst[i];
      int b = (int)((float)d * inv8n);
      b = b > 7 ? 7 : b;
      if (b == bin) {
        const int idx = atomicAdd(&cnt[d], 1);
        __builtin_nontemporal_store((u16)src[i], &col[(size_t)d * CSR_CAP + idx]);
      }
    }
  } else {
    int pb = bid - gemmNB - fillNB;
    if (pb < 64) {
      pack_w_elem(W2, Wp2, 128, 8, pb * 256 + tid);
    } else {
      const int idx = (pb - 64) * 256 + tid;
      if (idx < 128 * 48) pack_w_elem(W3, Wp3, 40, 3, idx);
    }
  }
}

// dnf[i] = rsqrt(cnt[i]+1); zero for padding rows.
__global__ __launch_bounds__(256) void k_dinvf(const int* __restrict__ cnt,
                                               float* __restrict__ dnf,
                                               int n, int rows_pad) {
  int i = blockIdx.x * 256 + threadIdx.x;
  if (i < rows_pad) dnf[i] = (i < n) ? rsqrtf((float)(cnt[i] + 1)) : 0.f;
}

// -------- AGGEMM: agg 32 nodes -> bf16 H-tile in LDS -> MFMA -> T̂out --------
// PRESCALED: input rows are already dn_s-scaled (pure add); else gather dnf[s].
// Output rows scaled by dnf[row] (=> T̂ for the next layer).
template <int FOUT, bool PRESCALED>
__global__ __launch_bounds__(256) void k_aggemm(const short* __restrict__ Tb,
                                                const int* __restrict__ cnt,
                                                const u16* __restrict__ col,
                                                const float* __restrict__ dnf,
                                                const float* __restrict__ bias,
                                                const short* __restrict__ Wp,
                                                short* __restrict__ Tout, int n) {
  __shared__ short Ht[32 * 128];  // 8 KB, XOR-swizzled rows
  const int tid = threadIdx.x;
  const int base = blockIdx.x * 32;

  // ---- aggregation: 16 lanes/node, 2 passes of 16 nodes, 4x unrolled ----
#pragma unroll
  for (int pass = 0; pass < 2; ++pass) {
    const int nl = pass * 16 + (tid >> 4);  // node-local 0..31
    const int node = base + nl;
    const int c8 = tid & 15;
    const int c0 = c8 * 8;
    float r[8];
#pragma unroll
    for (int j = 0; j < 8; ++j) r[j] = 0.f;
    if (node < n) {
      const int cn = cnt[node];
      const float dn = dnf[node];
      float acc[8];
      {
        const s8v v = *(const s8v*)(Tb + (size_t)node * 128 + c0);  // self
#pragma unroll
        for (int j = 0; j < 8; ++j)
          acc[j] = (PRESCALED ? 1.f : dn) * b2f((unsigned short)v[j]);
      }
      const u16* cp = col + (size_t)node * CSR_CAP;
      int k = 0;
      for (; k + 4 <= cn; k += 4) {
        const int s0 = cp[k], s1 = cp[k + 1], s2 = cp[k + 2], s3 = cp[k + 3];
        const s8v v0 = *(const s8v*)(Tb + (size_t)s0 * 128 + c0);
        const s8v v1 = *(const s8v*)(Tb + (size_t)s1 * 128 + c0);
        const s8v v2 = *(const s8v*)(Tb + (size_t)s2 * 128 + c0);
        const s8v v3 = *(const s8v*)(Tb + (size_t)s3 * 128 + c0);
        if (PRESCALED) {
#pragma unroll
          for (int j = 0; j < 8; ++j)
            acc[j] += b2f((unsigned short)v0[j]) + b2f((unsigned short)v1[j]) +
                      b2f((unsigned short)v2[j]) + b2f((unsigned short)v3[j]);
        } else {
          const float d0 = dnf[s0], d1 = dnf[s1], d2 = dnf[s2], d3 = dnf[s3];
#pragma unroll
          for (int j = 0; j < 8; ++j)
            acc[j] += d0 * b2f((unsigned short)v0[j]) +
                      d1 * b2f((unsigned short)v1[j]) +
                      d2 * b2f((unsigned short)v2[j]) +
                      d3 * b2f((unsigned short)v3[j]);
        }
      }
      for (; k < cn; ++k) {
        const int s = cp[k];
        const s8v v = *(const s8v*)(Tb + (size_t)s * 128 + c0);
        const float ds = PRESCALED ? 1.f : dnf[s];
#pragma unroll
        for (int j = 0; j < 8; ++j) acc[j] += ds * b2f((unsigned short)v[j]);
      }
#pragma unroll
      for (int j = 0; j < 8; ++j)
        r[j] = fmaxf(acc[j] * dn + bias[c0 + j], 0.f);  // relu (H1/H2)
    }
    s8v o;
#pragma unroll
    for (int j = 0; j < 8; ++j) o[j] = (short)f2b(r[j]);
    *(s8v*)((char*)Ht + nl * 256 + ((c0 * 2) ^ ((nl & 7) << 4))) = o;
  }
  __syncthreads();

  // ---- GEMM: 2 tiles x 16 rows; waves split col-range; output *dnf[row] ----
  constexpr int NCT = FOUT / 16;
  const int wid = tid >> 6, lane = tid & 63;
  const int tile = wid >> 1;
  int ct0, nct;
  if (FOUT == 128) { ct0 = (wid & 1) * 4; nct = 4; }
  else { ct0 = 0; nct = (wid & 1) ? 0 : NCT; }  // 48-wide: waves 1,3 idle
  if (nct > 0) {
    f4v acc[4];
#pragma unroll
    for (int j = 0; j < 4; ++j) acc[j] = (f4v)(0.f);
    const int lrow = tile * 16 + (lane & 15);
    const int kbase = (lane >> 4) * 8;
#pragma unroll
    for (int ks = 0; ks < 4; ++ks) {
      const int kcol = kbase + ks * 32;
      const s8v af = *(const s8v*)((const char*)Ht + lrow * 256 +
                                   ((kcol * 2) ^ ((lrow & 7) << 4)));
#pragma unroll
      for (int j = 0; j < 4; ++j) {
        if (j < nct) {
          const s8v bf =
              *(const s8v*)(Wp + ((ks * NCT + ct0 + j) * 64 + lane) * 8);
          acc[j] = mfma16(af, bf, acc[j]);
        }
      }
    }
    const int crow0 = base + tile * 16 + (lane >> 4) * 4;
    const int ccol = lane & 15;
#pragma unroll
    for (int r = 0; r < 4; ++r) {
      const float sc = dnf[crow0 + r];  // prescale for next layer
      short* orow = Tout + (size_t)(crow0 + r) * FOUT + ccol;
#pragma unroll
      for (int j = 0; j < 4; ++j)
        if (j < nct) orow[(ct0 + j) * 16] = (short)f2b(acc[j][r] * sc);
    }
  }
}

// ------- agg3 + log_softmax (T3hat prescaled, flat 48-wide, 40 valid) -------
__global__ __launch_bounds__(256) void k_agg3_lsm(const short* __restrict__ Tb,
                                                  const int* __restrict__ cnt,
                                                  const u16* __restrict__ col,
                                                  const float* __restrict__ dnf,
                                                  const float* __restrict__ bias,
                                                  float* __restrict__ out, int n) {
  const int gtid = blockIdx.x * 256 + threadIdx.x;
  const int node = gtid >> 3;
  const int c8 = gtid & 7;
  if (node >= n) return;
  const int c0 = c8 * 8;
  const bool valid = c8 < 5;
  const int cn = cnt[node];
  const float dn = dnf[node];
  float acc[8];
#pragma unroll
  for (int j = 0; j < 8; ++j) acc[j] = 0.f;
  const u16* cp = col + (size_t)node * CSR_CAP;
  if (valid) {
    const s8v v = *(const s8v*)(Tb + (size_t)node * 48 + c0);
#pragma unroll
    for (int j = 0; j < 8; ++j) acc[j] = b2f((unsigned short)v[j]);
    int k = 0;
    for (; k + 4 <= cn; k += 4) {
      const int s0 = cp[k], s1 = cp[k + 1], s2 = cp[k + 2], s3 = cp[k + 3];
      const s8v v0 = *(const s8v*)(Tb + (size_t)s0 * 48 + c0);
      const s8v v1 = *(const s8v*)(Tb + (size_t)s1 * 48 + c0);
      const s8v v2 = *(const s8v*)(Tb + (size_t)s2 * 48 + c0);
      const s8v v3 = *(const s8v*)(Tb + (size_t)s3 * 48 + c0);
#pragma unroll
      for (int j = 0; j < 8; ++j)
        acc[j] += b2f((unsigned short)v0[j]) + b2f((unsigned short)v1[j]) +
                  b2f((unsigned short)v2[j]) + b2f((unsigned short)v3[j]);
    }
    for (; k < cn; ++k) {
      const int s = cp[k];
      const s8v v = *(const s8v*)(Tb + (size_t)s * 48 + c0);
#pragma unroll
      for (int j = 0; j < 8; ++j) acc[j] += b2f((unsigned short)v[j]);
    }
  }
  float r[8];
  float m = -INFINITY;
#pragma unroll
  for (int j = 0; j < 8; ++j) {
    r[j] = valid ? (acc[j] * dn + bias[c0 + j]) : -INFINITY;
    m = fmaxf(m, r[j]);
  }
#pragma unroll
  for (int w = 1; w < 8; w <<= 1) m = fmaxf(m, __shfl_xor(m, w, 64));
  float s = 0.f;
#pragma unroll
  for (int j = 0; j < 8; ++j) s += expf(r[j] - m);
#pragma unroll
  for (int w = 1; w < 8; w <<= 1) s += __shfl_xor(s, w, 64);
  const float ls = logf(s);
  if (valid) {
    float* op = out + (size_t)node * 40 + c0;
    *(float4*)op = make_float4(r[0] - m - ls, r[1] - m - ls, r[2] - m - ls,
                               r[3] - m - ls);
    *(float4*)(op + 4) = make_float4(r[4] - m - ls, r[5] - m - ls,
                                     r[6] - m - ls, r[7] - m - ls);
  }
}

extern "C" void kernel_launch(void* const* d_in, const int* in_sizes, int n_in,
                              void* d_out, int out_size, void* d_ws,
                              size_t ws_size, hipStream_t stream) {
  const float* x  = (const float*)d_in[0];
  const int*   ei = (const int*)d_in[1];
  const float* W1 = (const float*)d_in[2];
  const float* b1 = (const float*)d_in[3];
  const float* W2 = (const float*)d_in[4];
  const float* b2 = (const float*)d_in[5];
  const float* W3 = (const float*)d_in[6];
  const float* b3 = (const float*)d_in[7];
  float* out = (float*)d_out;

  const int n = in_sizes[0] / 128;  // 50000
  const int e = in_sizes[1] / 2;    // 800000
  const int* src = ei;
  const int* dst = ei + e;

  char* ws = (char*)d_ws;
  size_t off = 0;
  auto carve = [&](size_t bytes) -> void* {
    void* p = ws + off;
    off = (off + bytes + 255) & ~(size_t)255;
    return p;
  };
  const int nb32 = (n + 31) / 32;            // aggemm blocks (1563)
  const int rows_pad = nb32 * 32;            // 50016

  int*   cnt = (int*)carve((size_t)n * 4);
  float* dnf = (float*)carve((size_t)rows_pad * 4);
  u16*   col = (u16*)carve((size_t)n * CSR_CAP * 2);  // 6.4 MB padded CSR
  short* A   = (short*)carve((size_t)rows_pad * 128 * 2);  // T2hat
  short* B   = (short*)carve((size_t)rows_pad * 128 * 2);  // T1, then T3hat(48)
  short* Wp2 = (short*)carve(128 * 128 * 2);
  short* Wp3 = (short*)carve(128 * 48 * 2);

  const int nRowTiles = (n + 15) / 16;       // 3125
  const int gemmNB = (nRowTiles + 3) / 4;    // 782
  const int fillNB = 2048;                   // 256 scan-blocks x 8 bins
  const int soupNB = gemmNB + fillNB + 64 + 24;

  hipMemsetAsync(cnt, 0, (size_t)n * 4, stream);
  k_soup<<<soupNB, 256, 0, stream>>>(x, W1, B, nRowTiles, gemmNB, src, dst,
                                     cnt, col, e, 8.0f / (float)n, fillNB,
                                     W2, Wp2, W3, Wp3);
  k_dinvf<<<(rows_pad + 255) / 256, 256, 0, stream>>>(cnt, dnf, n, rows_pad);
  // Layer 1 agg (unscaled input, dnf gather) + gemm2 -> T2hat
  k_aggemm<128, false><<<nb32, 256, 0, stream>>>(B, cnt, col, dnf, b1, Wp2, A, n);
  // Layer 2 agg (prescaled) + gemm3 -> T3hat (flat 48)
  k_aggemm<48, true><<<nb32, 256, 0, stream>>>(A, cnt, col, dnf, b2, Wp3, B, n);
  // Layer 3 agg (prescaled) + log_softmax -> out
  k_agg3_lsm<<<((size_t)n * 8 + 255) / 256, 256, 0, stream>>>(B, cnt, col, dnf,
                                                              b3, out, n);
}